// Round 1
// baseline (149.125 us; speedup 1.0000x reference)
//
#include <hip/hip_runtime.h>
#include <hip/hip_bf16.h>

// Problem constants: B=4, C=16, F=35, G=72, D=24, T=256
#define NB 4
#define NC 16
#define NF 35
#define NG 72
#define ND3 13824   // 24^3
#define NT 256
#define FP 36       // padded row stride (36*4B = 144B, multiple of 16 -> s_load_dwordx4-friendly)

// SELU constants (match jax.nn.selu)
#define SELU_LAMBDA 1.0507009873554805f
#define SELU_LA     1.7580993408473766f   // lambda * alpha

// ---------------------------------------------------------------------------
// Prep kernel (one tiny block): compute per-(b,c) time bias tb = t @ W_time^T
// + b_time, and write 16B-aligned padded copies of A_ift and A_ft^T into ws.
// ws layout (floats): [0,64) tb | [64, 64+72*36) A_ift padded | next 72*36 A_ftT padded
// ---------------------------------------------------------------------------
__global__ __launch_bounds__(256) void fta_prep(
    const float* __restrict__ t, const float* __restrict__ A_ift,
    const float* __restrict__ A_ft, const float* __restrict__ W_time,
    const float* __restrict__ b_time, float* __restrict__ ws) {
  const int tid = threadIdx.x;
  if (tid < NB * NC) {
    const int b = tid / NC, c = tid % NC;
    float s = b_time[c];
    #pragma unroll 4
    for (int k = 0; k < NT; ++k) s = fmaf(t[b * NT + k], W_time[c * NT + k], s);
    ws[tid] = s;
  }
  float* aift_p = ws + 64;
  float* aftT_p = ws + 64 + NG * FP;
  for (int i = tid; i < NG * FP; i += 256) {
    const int g = i / FP, f = i % FP;
    aift_p[i] = (f < NF) ? A_ift[g * NF + f] : 0.0f;
    aftT_p[i] = (f < NF) ? A_ft[f * NG + g] : 0.0f;  // transpose of A_ft
  }
}

// ---------------------------------------------------------------------------
// Fused main kernel: one thread per voxel per (b,c).
//   x[f] <- coalesced loads (lane-contiguous voxel index)
//   for g: v = tb + sum_f A_ift[g,f]*x[f]; y = selu(v); acc[f] += A_ftT[g,f]*y
// Matrix reads use wave-uniform indices -> compiler emits scalar (s_load)
// fetches through the constant cache, keeping the VALU as the only hot pipe.
// ---------------------------------------------------------------------------
__global__ __launch_bounds__(256) void fta_fused(
    const float* __restrict__ x_hat, const float* __restrict__ ws,
    float* __restrict__ out) {
  const int bc  = blockIdx.y;                       // 0..63  (b*C + c)
  const int vox = blockIdx.x * 256 + threadIdx.x;   // 0..13823 (54*256 exact)

  const float tb = ws[bc];
  const float* __restrict__ aift = (const float*)__builtin_assume_aligned(ws + 64, 16);
  const float* __restrict__ aftT = (const float*)__builtin_assume_aligned(ws + 64 + NG * FP, 16);

  const float* __restrict__ xp = x_hat + (size_t)bc * NF * ND3 + vox;

  float xr[NF];
  #pragma unroll
  for (int f = 0; f < NF; ++f) xr[f] = xp[(size_t)f * ND3];

  float acc[NF];
  #pragma unroll
  for (int f = 0; f < NF; ++f) acc[f] = 0.0f;

  #pragma unroll 2
  for (int g = 0; g < NG; ++g) {
    const float* __restrict__ arow = aift + g * FP;
    float v = tb;
    #pragma unroll
    for (int f = 0; f < NF; ++f) v = fmaf(arow[f], xr[f], v);

    // SELU: lambda * (v > 0 ? v : alpha*(exp(v)-1))
    const float e   = __expf(v);
    const float neg = fmaf(SELU_LA, e, -SELU_LA);   // lambda*alpha*(e-1)
    const float pos = SELU_LAMBDA * v;
    const float y   = (v > 0.0f) ? pos : neg;

    const float* __restrict__ brow = aftT + g * FP;
    #pragma unroll
    for (int f = 0; f < NF; ++f) acc[f] = fmaf(brow[f], y, acc[f]);
  }

  float* __restrict__ op = out + (size_t)bc * NF * ND3 + vox;
  #pragma unroll
  for (int f = 0; f < NF; ++f) op[(size_t)f * ND3] = acc[f];
}

extern "C" void kernel_launch(void* const* d_in, const int* in_sizes, int n_in,
                              void* d_out, int out_size, void* d_ws, size_t ws_size,
                              hipStream_t stream) {
  const float* x_hat  = (const float*)d_in[0];
  const float* t      = (const float*)d_in[1];
  const float* A_ift  = (const float*)d_in[2];
  const float* A_ft   = (const float*)d_in[3];
  const float* W_time = (const float*)d_in[4];
  const float* b_time = (const float*)d_in[5];
  float* out = (float*)d_out;
  float* ws  = (float*)d_ws;   // needs 64 + 2*72*36 = 5248 floats = 21 KB

  fta_prep<<<1, 256, 0, stream>>>(t, A_ift, A_ft, W_time, b_time, ws);

  dim3 grid(ND3 / 256, NB * NC);   // (54, 64)
  fta_fused<<<grid, 256, 0, stream>>>(x_hat, ws, out);
}